// Round 5
// baseline (174.578 us; speedup 1.0000x reference)
//
#include <hip/hip_runtime.h>
#include <stdint.h>

#define M_DIM 16384
#define N_DIM 1024
#define K_DIM 1024

#define BM 128
#define BN 128
#define BK 64
#define LDSW 20   // dwords per LDS row: 64B data + 16B pad = 80B. Banks for
                  // frag reads = (20*row + 4*ch) % 32 -> 2-way max (free);
                  // unpadded 64B rows were 8-way (2.9x cost, G4).

using i32x4 = __attribute__((ext_vector_type(4))) int;

__device__ __forceinline__ int pack4(int4 v) {
    return (v.x & 0xFF) | ((v.y & 0xFF) << 8) | ((v.z & 0xFF) << 16) | ((v.w & 0xFF) << 24);
}

// ------------- pack w + corr: one block per output column ----------
// corr[n] = bias[n] - 3 * sum_k w[n,k]   (weight_zp=0 -> exact fold)
__global__ __launch_bounds__(256) void pack_w_corr_kernel(const int* __restrict__ w,
                                                          const int* __restrict__ bias,
                                                          int8_t* __restrict__ wq,
                                                          int* __restrict__ corr) {
    int col = blockIdx.x;
    int t = threadIdx.x;
    int4 v = ((const int4*)(w + (size_t)col * K_DIM))[t];  // 4 elems
    ((int*)(wq + (size_t)col * K_DIM))[t] = pack4(v);
    int s = v.x + v.y + v.z + v.w;
#pragma unroll
    for (int m = 1; m < 64; m <<= 1) s += __shfl_xor(s, m);
    __shared__ int partial[4];
    if ((t & 63) == 0) partial[t >> 6] = s;
    __syncthreads();
    if (t == 0) {
        int total = partial[0] + partial[1] + partial[2] + partial[3];
        corr[col] = bias[col] - 3 * total;
    }
}

// ---------------- fused GEMM: pack x in-register, i8 MFMA, requant ----------------
// 128x128 tile, BK=64, 4 waves (2x2 of 64x64), mfma_i32_16x16x64_i8.
// Double-buffered LDS (padded rows), 1 barrier per K-step, T14 issue-early.
__global__ __launch_bounds__(256, 2) void gemm_fused_kernel(const int* __restrict__ X,
                                                            const int8_t* __restrict__ Wq,
                                                            const int* __restrict__ corr,
                                                            int* __restrict__ out) {
    __shared__ int Asm[2][BM * LDSW];   // 2 x 10240 B
    __shared__ int Bsm[2][BN * LDSW];

    int bid = blockIdx.x;
    // XCD-bijective swizzle (nwg=1024 % 8 == 0): XCD x gets mtiles [x*16, x*16+16),
    // all 8 ntiles -> per-XCD L2 set: 16 A-panels (8MB int32 in L2-stream) + 1MB B.
    int swz = (bid & 7) * 128 + (bid >> 3);
    int m0 = (swz >> 3) * BM;
    int n0 = (swz & 7) * BN;

    int tid = threadIdx.x;
    int lane = tid & 63;
    int wave = tid >> 6;
    int wm = wave >> 1;     // 0..1
    int wn = wave & 1;      // 0..1
    int r16 = lane & 15;
    int krow = lane >> 4;   // 0..3 -> k-offset krow*16 bytes

    i32x4 acc[4][4];
#pragma unroll
    for (int i = 0; i < 4; ++i)
#pragma unroll
        for (int j = 0; j < 4; ++j)
            acc[i][j] = (i32x4){0, 0, 0, 0};

    // A staging: 8 int4 loads/thread/K-step. load i covers dword f = i*256+tid:
    //   row = f>>4 = i*16 + (tid>>4), dcol = f&15  (each instr: 4 rows x 256B contiguous)
    int arow = tid >> 4;
    int adcol = tid & 15;
    const int* Abase = X + (size_t)(m0 + arow) * K_DIM + adcol * 4;
    // B staging (packed i8): 2 int4 loads/thread/K-step. f = i*256+tid (16B units):
    //   row = f>>2 = i*64 + (tid>>2), dc4 = f&3
    int brow = tid >> 2;
    int bdc4 = tid & 3;
    const int8_t* Bbase = Wq + (size_t)(n0 + brow) * K_DIM + bdc4 * 16;

    int4 areg[8];
    int4 breg[2];

#define LOAD_TILE(kt)                                                              \
    {                                                                              \
        _Pragma("unroll") for (int i = 0; i < 8; ++i)                              \
            areg[i] = *(const int4*)(Abase + (size_t)i * 16 * K_DIM + (kt) * BK);  \
        _Pragma("unroll") for (int i = 0; i < 2; ++i)                              \
            breg[i] = *(const int4*)(Bbase + (size_t)i * 64 * K_DIM + (kt) * BK);  \
    }

#define WRITE_TILE(buf)                                                            \
    {                                                                              \
        _Pragma("unroll") for (int i = 0; i < 8; ++i)                              \
            Asm[buf][(i * 16 + arow) * LDSW + adcol] = pack4(areg[i]);             \
        _Pragma("unroll") for (int i = 0; i < 2; ++i)                              \
            *(int4*)&Bsm[buf][(i * 64 + brow) * LDSW + bdc4 * 4] = breg[i];        \
    }

    LOAD_TILE(0);
    WRITE_TILE(0);

    for (int kt = 0; kt < K_DIM / BK; ++kt) {
        int cur = kt & 1;
        __syncthreads();                 // buf[cur] ready for all
        if (kt < 15) LOAD_TILE(kt + 1);  // issue-early: hide HBM under ds_read+MFMA

        i32x4 afr[4], bfr[4];
#pragma unroll
        for (int i = 0; i < 4; ++i) {
            afr[i] = *(const i32x4*)&Asm[cur][(wm * 64 + i * 16 + r16) * LDSW + krow * 4];
            bfr[i] = *(const i32x4*)&Bsm[cur][(wn * 64 + i * 16 + r16) * LDSW + krow * 4];
        }
#pragma unroll
        for (int i = 0; i < 4; ++i)
#pragma unroll
            for (int j = 0; j < 4; ++j)
                acc[i][j] = __builtin_amdgcn_mfma_i32_16x16x64_i8(afr[i], bfr[j], acc[i][j], 0, 0, 0);

        if (kt < 15) WRITE_TILE(cur ^ 1);  // compiler waits vmcnt here; next
                                           // barrier (top of kt+1) publishes
    }

    // Epilogue: C/D layout col = lane&15, row = (lane>>4)*4 + reg.
    int col16 = lane & 15;
    int rbase = (lane >> 4) * 4;
#pragma unroll
    for (int j = 0; j < 4; ++j) {
        int c = n0 + wn * 64 + j * 16 + col16;
        int cr = corr[c];
#pragma unroll
        for (int i = 0; i < 4; ++i) {
            int rrow = m0 + wm * 64 + i * 16 + rbase;
#pragma unroll
            for (int r = 0; r < 4; ++r) {
                int t = acc[i][j][r] + cr;
                int res = ((t * 10) >> 10) - 5;       // floor((acc*10)/1024) + OUTPUT_ZP
                res = res < -128 ? -128 : (res > 127 ? 127 : res);
                out[(size_t)(rrow + r) * N_DIM + c] = res;
            }
        }
    }
#undef LOAD_TILE
#undef WRITE_TILE
}

extern "C" void kernel_launch(void* const* d_in, const int* in_sizes, int n_in,
                              void* d_out, int out_size, void* d_ws, size_t ws_size,
                              hipStream_t stream) {
    (void)in_sizes; (void)n_in; (void)out_size; (void)ws_size;
    const int* x    = (const int*)d_in[0];
    const int* w    = (const int*)d_in[1];
    const int* bias = (const int*)d_in[2];
    int* out = (int*)d_out;

    int8_t* wq = (int8_t*)d_ws;                          // 1 MiB
    int* corr  = (int*)(wq + (size_t)N_DIM * K_DIM);     // 4 KiB

    pack_w_corr_kernel<<<N_DIM, 256, 0, stream>>>(w, bias, wq, corr);
    gemm_fused_kernel<<<(M_DIM / BM) * (N_DIM / BN), 256, 0, stream>>>(x, wq, corr, out);
}